// Round 5
// baseline (158.224 us; speedup 1.0000x reference)
//
#include <hip/hip_runtime.h>

constexpr int N_NODES  = 50000;
constexpr int N_EDGES  = 1600000;
constexpr int F_IN     = 48;
constexpr int C1_OUT   = 16;

// ---- binning geometry -----------------------------------------------------
constexpr int BNODES    = 64;                     // nodes per bin; bin = dst >> 6
constexpr int NBINS     = 782;                    // ceil(50000/64)
constexpr int FILL_BLKS = 256;
constexpr int EPB       = N_EDGES / FILL_BLKS;    // 6250 (exact)
constexpr int SCAP      = 16;                     // slots/cell = one 64B line; mean 8
constexpr int OCAP      = 8192;                   // overflow list (expected ~700)
constexpr int BIN_INTS  = FILL_BLKS * SCAP;       // 4096 ints per bin (16 KB)
constexpr int LCAP      = 2600;                   // LDS CSR entries: mean 2048, +12 sigma
constexpr int XW_BLKS   = 49;                     // 49*1024 >= 50000

// ---- workspace layout (~16.25 MB; offsets 256B-aligned) --------------------
constexpr size_t OCNT_OFF  = 0;
constexpr size_t OFLOW_OFF = 256;
constexpr size_t PART_OFF  = OFLOW_OFF + (size_t)OCAP * 4;          // 33024
constexpr size_t XW_OFF    = PART_OFF + 4096;                        // 37120
constexpr size_t CNT_OFF   = XW_OFF + (size_t)N_NODES * C1_OUT * 4;  // +3.2MB
constexpr size_t GSLOT_OFF = CNT_OFF + (size_t)NBINS * FILL_BLKS;    // +200192

// ---------------------------------------------------------------------------
// xw[n] = x[n] @ W  (fold linear map before gather; 3.2 MB table)
// ---------------------------------------------------------------------------
__device__ __forceinline__ void xw_body(int n, const float* __restrict__ x,
                                        const float* __restrict__ W,
                                        float* __restrict__ xw)
{
    const float4* xr = (const float4*)(x + (long)n * F_IN);
    float h[C1_OUT];
    #pragma unroll
    for (int c = 0; c < C1_OUT; ++c) h[c] = 0.f;
    #pragma unroll
    for (int k = 0; k < F_IN / 4; ++k) {
        float4 v = xr[k];
        #pragma unroll
        for (int c = 0; c < C1_OUT; ++c) {
            h[c] = fmaf(v.x, W[(4*k+0)*C1_OUT + c],
                   fmaf(v.y, W[(4*k+1)*C1_OUT + c],
                   fmaf(v.z, W[(4*k+2)*C1_OUT + c],
                   fmaf(v.w, W[(4*k+3)*C1_OUT + c], h[c]))));
        }
    }
    float4* o = (float4*)(xw + (long)n * C1_OUT);
    o[0] = make_float4(h[0],  h[1],  h[2],  h[3]);
    o[1] = make_float4(h[4],  h[5],  h[6],  h[7]);
    o[2] = make_float4(h[8],  h[9],  h[10], h[11]);
    o[3] = make_float4(h[12], h[13], h[14], h[15]);
}

// ---------------------------------------------------------------------------
// Pass 1: deterministic per-(bin,block) slot scatter, ZERO global atomics.
// Packed edge: (src<<6)|(dst&63); bin = dst>>6. No padding: per-cell byte
// counts (cnt2d) are written unconditionally (re-poison safe); agg bounds
// processing by count so garbage slots are never decoded. xw fused in a
// disjoint block range.
// ---------------------------------------------------------------------------
__global__ __launch_bounds__(1024)
void k_fill_xw(const int* __restrict__ src, const int* __restrict__ dst,
               int* __restrict__ gslot, unsigned char* __restrict__ cnt2d,
               int* __restrict__ ocnt, unsigned int* __restrict__ oflow,
               const float* __restrict__ x, const float* __restrict__ W,
               float* __restrict__ xw)
{
    __shared__ int lcnt[NBINS];

    if (blockIdx.x >= FILL_BLKS) {               // fused xw range
        int n = (blockIdx.x - FILL_BLKS) * 1024 + threadIdx.x;
        if (n < N_NODES) xw_body(n, x, W, xw);
        return;
    }

    int tid = threadIdx.x;
    if (tid < NBINS) lcnt[tid] = 0;
    __syncthreads();

    int e0 = blockIdx.x * EPB;
    for (int i = tid; i < EPB; i += 1024) {
        int e = e0 + i;
        int s = src[e], d = dst[e];
        int b = d >> 6;
        int p = atomicAdd(&lcnt[b], 1);
        if (p < SCAP) {
            gslot[((size_t)b * FILL_BLKS + blockIdx.x) * SCAP + p] = (s << 6) | (d & 63);
        } else {                                  // ~700 edges expected
            int g = atomicAdd(ocnt, 1);
            if (g < OCAP) oflow[g] = ((unsigned)s << 16) | (unsigned)d;
        }
    }
    __syncthreads();
    for (int b = tid; b < NBINS; b += 1024) {
        int c = lcnt[b];
        cnt2d[(size_t)b * FILL_BLKS + blockIdx.x] =
            (unsigned char)((c < SCAP) ? c : SCAP);
    }
}

// ---------------------------------------------------------------------------
// Pass 2: one block (256 thr, 4 waves) per 64-node bin; 782 blocks -> ~3/CU.
//   A: coalesced count load (256 B) + blind coalesced int4 load of the bin's
//      4096 slots (16 KB); garbage beyond count never decoded.
//   B: LDS CSR rebuild: int hist -> 1-wave scan -> cursor scatter.
//   C: wave-per-node register aggregation + shuffle reduce + fused epilogue.
// ---------------------------------------------------------------------------
__device__ __forceinline__ float node_epilogue(
    float4 a, int n, float inv, const float* __restrict__ xw,
    const float* __restrict__ bias, const float* __restrict__ lin1_w,
    const float* __restrict__ lin1_b, const float* __restrict__ out_w,
    const float* __restrict__ out_b, const float* __restrict__ labels,
    const float* __restrict__ weights, float* __restrict__ out,
    float* s16, int lane)
{
    if (lane < 4) {
        float4 v  = ((const float4*)(xw + (size_t)n * C1_OUT))[lane]; // self loop
        float4 b4 = ((const float4*)bias)[lane];
        float4 h;
        h.x = fmaxf(fmaf(a.x + v.x, inv, b4.x), 0.f);
        h.y = fmaxf(fmaf(a.y + v.y, inv, b4.y), 0.f);
        h.z = fmaxf(fmaf(a.z + v.z, inv, b4.z), 0.f);
        h.w = fmaxf(fmaf(a.w + v.w, inv, b4.w), 0.f);
        ((float4*)s16)[lane] = h;
    }
    float x2 = 0.f;
    if (lane < 8) {
        x2 = lin1_b[lane];
        #pragma unroll
        for (int k = 0; k < C1_OUT; ++k)
            x2 = fmaf(s16[k], lin1_w[k * 8 + lane], x2);
        x2 = fmaxf(x2, 0.f) * out_w[lane];
    }
    x2 += __shfl_xor(x2, 1, 64);
    x2 += __shfl_xor(x2, 2, 64);
    x2 += __shfl_xor(x2, 4, 64);
    float ret = 0.f;
    if (lane == 0) {
        float z = x2 + out_b[0];
        float p = 1.f / (1.f + __expf(-z));
        out[1 + n] = p;
        const float eps = 1e-7f;
        float pc = fminf(fmaxf(p, eps), 1.f - eps);
        float y  = labels[n];
        ret = weights[n] * (-(y * __logf(pc) + (1.f - y) * __logf(1.f - pc)));
    }
    return ret;
}

__global__ __launch_bounds__(256)
void k_agg(const int* __restrict__ gslot, const unsigned char* __restrict__ cnt2d,
           const int* __restrict__ ocnt, const unsigned int* __restrict__ oflow,
           const float* __restrict__ xw,
           const float* __restrict__ bias, const float* __restrict__ lin1_w,
           const float* __restrict__ lin1_b, const float* __restrict__ out_w,
           const float* __restrict__ out_b, const float* __restrict__ labels,
           const float* __restrict__ weights, float* __restrict__ out,
           float* __restrict__ partials)
{
    __shared__ int   hist[BNODES];
    __shared__ int   cursor[BNODES];
    __shared__ int   scnt[FILL_BLKS];            // per-cell valid counts
    __shared__ unsigned short lbuk[LCAP];        // 5.2 KB
    __shared__ float s16[4][16];
    __shared__ float sLossW[4];

    int B = blockIdx.x, tid = threadIdx.x, lane = tid & 63, w = tid >> 6;

    if (tid < BNODES) hist[tid] = 0;
    scnt[tid] = cnt2d[(size_t)B * FILL_BLKS + tid];
    __syncthreads();

    // A: blind coalesced load of the bin's 4096 slots (1024 int4, 4/thread)
    // int4 #j covers ints [4j,4j+4) -> cell j>>2, slot base (j&3)*4.
    const int4* sp = (const int4*)(gslot + (size_t)B * BIN_INTS);
    int4 q0 = sp[tid], q1 = sp[tid + 256], q2 = sp[tid + 512], q3 = sp[tid + 768];
    int r0 = scnt[(tid)          >> 2] - ((tid & 3) << 2);
    int r1 = scnt[(tid + 256)    >> 2] - ((tid & 3) << 2);
    int r2 = scnt[(tid + 512)    >> 2] - ((tid & 3) << 2);
    int r3 = scnt[(tid + 768)    >> 2] - ((tid & 3) << 2);

    int oc = *ocnt; if (oc > OCAP) oc = OCAP;

    // B1: histogram (count-bounded; garbage never decoded)
    #define H4(q, r) { if (0 < (r)) atomicAdd(&hist[(q).x & 63], 1); \
                       if (1 < (r)) atomicAdd(&hist[(q).y & 63], 1); \
                       if (2 < (r)) atomicAdd(&hist[(q).z & 63], 1); \
                       if (3 < (r)) atomicAdd(&hist[(q).w & 63], 1); }
    H4(q0, r0); H4(q1, r1); H4(q2, r2); H4(q3, r3);
    #undef H4
    for (int i = tid; i < oc; i += 256) {
        int d = (int)(oflow[i] & 0xffffu);
        if ((d >> 6) == B) atomicAdd(&hist[d & 63], 1);
    }
    __syncthreads();

    // B2: exclusive scan of 64 counts (wave 0)
    if (tid < 64) {
        int val = hist[tid];
        int s = val;
        #pragma unroll
        for (int off = 1; off < 64; off <<= 1) {
            int u = __shfl_up(s, off, 64);
            if (lane >= off) s += u;
        }
        cursor[tid] = s - val;
    }
    __syncthreads();

    // B3: scatter src into LDS CSR
    #define SC1(v) { int p = atomicAdd(&cursor[(v) & 63], 1); \
                     if (p < LCAP) lbuk[p] = (unsigned short)((unsigned)(v) >> 6); }
    #define SC4(q, r) { if (0 < (r)) SC1((q).x); if (1 < (r)) SC1((q).y); \
                        if (2 < (r)) SC1((q).z); if (3 < (r)) SC1((q).w); }
    SC4(q0, r0); SC4(q1, r1); SC4(q2, r2); SC4(q3, r3);
    #undef SC4
    for (int i = tid; i < oc; i += 256) {
        unsigned v = oflow[i];
        int d = (int)(v & 0xffffu);
        if ((d >> 6) == B) {
            int p = atomicAdd(&cursor[d & 63], 1);
            if (p < LCAP) lbuk[p] = (unsigned short)(v >> 16);
        }
    }
    #undef SC1
    __syncthreads();

    // C: wave-per-node register aggregation; 4 waves x 16 nodes
    int rslot = lane >> 2, c4 = lane & 3;
    float lossw = 0.f;
    for (int i = 0; i < 16; ++i) {
        int ln = w * 16 + i;
        int n = B * BNODES + ln;
        if (n >= N_NODES) break;                 // wave-uniform
        int deg   = hist[ln];
        int start = cursor[ln] - deg;            // cursor advanced by exactly deg
        float4 a = make_float4(0.f, 0.f, 0.f, 0.f);
        for (int j0 = 0; j0 < deg; j0 += 16) {
            int j = j0 + rslot;
            if (j < deg && start + j < LCAP) {
                int s = lbuk[start + j];
                float4 v = ((const float4*)(xw + (size_t)s * C1_OUT))[c4];
                a.x += v.x; a.y += v.y; a.z += v.z; a.w += v.w;
            }
        }
        #pragma unroll
        for (int off = 4; off < 64; off <<= 1) {
            a.x += __shfl_xor(a.x, off, 64);
            a.y += __shfl_xor(a.y, off, 64);
            a.z += __shfl_xor(a.z, off, 64);
            a.w += __shfl_xor(a.w, off, 64);
        }
        lossw += node_epilogue(a, n, 1.f / (float)(deg + 1), xw, bias, lin1_w,
                               lin1_b, out_w, out_b, labels, weights, out,
                               s16[w], lane);
    }
    if (lane == 0) sLossW[w] = lossw;
    __syncthreads();
    if (tid == 0)
        partials[B] = sLossW[0] + sLossW[1] + sLossW[2] + sLossW[3];
}

// ---------------------------------------------------------------------------
// Final loss reduce: one block over 782 partials.
// ---------------------------------------------------------------------------
__global__ __launch_bounds__(1024)
void k_loss_final(const float* __restrict__ partials, float* __restrict__ out)
{
    __shared__ float sw[16];
    int tid = threadIdx.x, lane = tid & 63, wv = tid >> 6;
    float s = (tid < NBINS) ? partials[tid] : 0.f;
    #pragma unroll
    for (int off = 32; off > 0; off >>= 1) s += __shfl_down(s, off, 64);
    if (lane == 0) sw[wv] = s;
    __syncthreads();
    if (tid == 0) {
        float t = 0.f;
        #pragma unroll
        for (int k = 0; k < 16; ++k) t += sw[k];
        out[0] = t / (float)N_NODES;
    }
}

// ===========================================================================
extern "C" void kernel_launch(void* const* d_in, const int* in_sizes, int n_in,
                              void* d_out, int out_size, void* d_ws, size_t ws_size,
                              hipStream_t stream)
{
    const float* x       = (const float*)d_in[0];
    const int*   eidx    = (const int*)  d_in[1];   // [2, E]
    const float* labels  = (const float*)d_in[2];
    const float* weights = (const float*)d_in[3];
    const float* W       = (const float*)d_in[4];
    // d_in[5] = u, d_in[6] = c: dead — softmax over H=1 axis is identically 1
    const float* bias    = (const float*)d_in[7];
    const float* lin1_w  = (const float*)d_in[8];
    const float* lin1_b  = (const float*)d_in[9];
    const float* out_w   = (const float*)d_in[10];
    const float* out_b   = (const float*)d_in[11];
    float* out = (float*)d_out;

    const int* src = eidx;
    const int* dst = eidx + N_EDGES;
    char* ws = (char*)d_ws;

    int*           ocnt     = (int*)(ws + OCNT_OFF);
    unsigned int*  oflow    = (unsigned int*)(ws + OFLOW_OFF);
    float*         partials = (float*)(ws + PART_OFF);
    float*         xw       = (float*)(ws + XW_OFF);
    unsigned char* cnt2d    = (unsigned char*)(ws + CNT_OFF);
    int*           gslot    = (int*)(ws + GSLOT_OFF);

    hipMemsetAsync(ocnt, 0, sizeof(int), stream);
    k_fill_xw<<<FILL_BLKS + XW_BLKS, 1024, 0, stream>>>(
        src, dst, gslot, cnt2d, ocnt, oflow, x, W, xw);
    k_agg<<<NBINS, 256, 0, stream>>>(
        gslot, cnt2d, ocnt, oflow, xw, bias, lin1_w, lin1_b,
        out_w, out_b, labels, weights, out, partials);
    k_loss_final<<<1, 1024, 0, stream>>>(partials, out);
}